// Round 8
// baseline (289.799 us; speedup 1.0000x reference)
//
#include <hip/hip_runtime.h>
#include <stdint.h>

#define NROWS 8192
#define DIM   512
#define NPART 128          // one slot per 64-column chunk

typedef __attribute__((ext_vector_type(8))) short short8;
typedef __attribute__((ext_vector_type(4))) float f32x4;
typedef unsigned int u32;

// ws layout (bytes). CPART shares space with PM (disjoint lifetimes).
#define OFF_EBF   0u           // 8192*512*2 = 8388608
#define OFF_X     8388608u     // CPART 4 MB (dead after k_clsred)
#define OFF_PM    8388608u     // 8192*128*4 = 4 MB
#define OFF_PL    12582912u    // 4 MB
#define OFF_CLS   16777216u    // 16*512*4 = 32768
#define OFF_CNT   16809984u    // 64
#define OFF_NRM   16810048u    // 8192*4 = 32768
#define OFF_BLK   16842816u    // 2048*4 = 8192

__device__ __forceinline__ unsigned short f2bf(float f) {
  u32 u = __float_as_uint(f);
  u32 r = (u + 0x7fffu + ((u >> 16) & 1u)) >> 16;
  return (unsigned short)r;
}

// ---------- kernel 1: fp32 -> bf16 + row norms^2 ----------
__global__ __launch_bounds__(256) void k_prep(const float* __restrict__ E,
                                              unsigned short* __restrict__ Ebf,
                                              float* __restrict__ nrm) {
  const int tid = threadIdx.x;
  const int lane = tid & 63;
  const int wid = tid >> 6;
  const int row = blockIdx.x * 4 + wid;
  const float4* src = (const float4*)(E + row * DIM + lane * 8);
  float4 v0 = src[0], v1 = src[1];
  float ns = v0.x*v0.x + v0.y*v0.y + v0.z*v0.z + v0.w*v0.w
           + v1.x*v1.x + v1.y*v1.y + v1.z*v1.z + v1.w*v1.w;
  u32 p0 = (u32)f2bf(v0.x) | ((u32)f2bf(v0.y) << 16);
  u32 p1 = (u32)f2bf(v0.z) | ((u32)f2bf(v0.w) << 16);
  u32 p2 = (u32)f2bf(v1.x) | ((u32)f2bf(v1.y) << 16);
  u32 p3 = (u32)f2bf(v1.z) | ((u32)f2bf(v1.w) << 16);
  *(uint4*)(Ebf + row * DIM + lane * 8) = make_uint4(p0, p1, p2, p3);
  #pragma unroll
  for (int s = 1; s < 64; s <<= 1) ns += __shfl_xor(ns, s);
  if (lane == 0) nrm[row] = ns;
}

// ---------- kernel 2: class partial sums via LDS float atomics ----------
__global__ __launch_bounds__(256) void k_cls(const float* __restrict__ E,
                                             const int* __restrict__ lab,
                                             float* __restrict__ Cpart,
                                             int* __restrict__ cnt) {
  __shared__ float lcls[16 * DIM];
  __shared__ int lcnt[16];
  const int t = threadIdx.x;          // owns dims {2t, 2t+1}
  const int b = blockIdx.x;           // 128 blocks x 64 rows
  const int i0 = b * 64;
  for (int k = t; k < 16 * DIM; k += 256) lcls[k] = 0.f;
  if (t < 16) lcnt[t] = 0;
  __syncthreads();
  if (t < 64) atomicAdd(&lcnt[lab[i0 + t]], 1);
  for (int r = 0; r < 64; ++r) {
    const int lbl = lab[i0 + r];
    const float2 v = *(const float2*)(E + (i0 + r) * DIM + t * 2);
    atomicAdd(&lcls[lbl * DIM + t * 2],     v.x);
    atomicAdd(&lcls[lbl * DIM + t * 2 + 1], v.y);
  }
  __syncthreads();
  for (int k = t; k < 16 * DIM; k += 256) Cpart[b * 8192 + k] = lcls[k];
  if (t < 16) atomicAdd(&cnt[t], lcnt[t]);
}

// ---------- kernel 2b: reduce class partials ----------
__global__ __launch_bounds__(256) void k_clsred(const float* __restrict__ Cpart,
                                                float* __restrict__ Cls) {
  const int idx = blockIdx.x * 256 + threadIdx.x;   // 32 blocks -> 8192 = 16*512
  float s = 0.f;
  #pragma unroll 8
  for (int b = 0; b < 128; ++b) s += Cpart[b * 8192 + idx];
  Cls[idx] = s;
}

// ---------- kernel 3: barrier-free streaming tiles, upper triangle ----------
// One wave per 64x64 tile-pair; fragments loaded straight from global (L1/L2).
// Each lane's MFMA fragment is a contiguous 16B row-slice of Ebf; lanes with
// g=0..3 consume one full 64B line -> line-perfect coalescing without LDS.
__global__ __launch_bounds__(256) void k_main(const unsigned short* __restrict__ Ebf,
                                              float* __restrict__ partM,
                                              float* __restrict__ partL) {
  // exact-cover triangle mapping: grid (65, 32) -> 2080 tiles (IT <= JT)
  const int x = blockIdx.x;        // 0..64
  const int y = blockIdx.y;        // 0..31
  int IT, JT;
  if (x < 64 - y) { IT = y;      JT = y + x; }
  else            { IT = 63 - y; JT = x - 1; }

  const int tid  = threadIdx.x;
  const int lane = tid & 63;
  const int wid  = tid >> 6;
  const int wm   = wid >> 1;
  const int wn   = wid & 1;
  const int g    = lane >> 4;  // 0..3
  const int l15  = lane & 15;

  const int a = IT * 2 + wm;   // row 64-chunk of this wave
  const int b = JT * 2 + wn;   // col 64-chunk of this wave
  const bool diagblk = (IT == JT);
  const bool diag64  = (a == b);

  const float C2 = 14.4269504088896f;  // (1/T) * log2(e)

  // per-lane fragment base pointers (row l15 of each 16-row group, k-chunk g)
  const unsigned short* pa0 = Ebf + (a * 64 + l15) * DIM + g * 8;
  const unsigned short* pb0 = Ebf + (b * 64 + l15) * DIM + g * 8;
  const unsigned short* pa1 = pa0 + 16 * DIM;
  const unsigned short* pa2 = pa0 + 32 * DIM;
  const unsigned short* pa3 = pa0 + 48 * DIM;
  const unsigned short* pb1 = pb0 + 16 * DIM;
  const unsigned short* pb2 = pb0 + 32 * DIM;
  const unsigned short* pb3 = pb0 + 48 * DIM;

  f32x4 acc[4][4];
  #pragma unroll
  for (int i = 0; i < 4; ++i)
    #pragma unroll
    for (int j = 0; j < 4; ++j) {
      f32x4 z = {0.f, 0.f, 0.f, 0.f};
      acc[i][j] = z;
    }

  #pragma unroll 4
  for (int ks = 0; ks < 16; ++ks) {    // K-step of 32: k = ks*32 + g*8
    short8 av0 = *(const short8*)(pa0 + ks * 32);
    short8 av1 = *(const short8*)(pa1 + ks * 32);
    short8 av2 = *(const short8*)(pa2 + ks * 32);
    short8 av3 = *(const short8*)(pa3 + ks * 32);
    short8 bv0 = *(const short8*)(pb0 + ks * 32);
    short8 bv1 = *(const short8*)(pb1 + ks * 32);
    short8 bv2 = *(const short8*)(pb2 + ks * 32);
    short8 bv3 = *(const short8*)(pb3 + ks * 32);
    acc[0][0] = __builtin_amdgcn_mfma_f32_16x16x32_bf16(av0, bv0, acc[0][0], 0, 0, 0);
    acc[0][1] = __builtin_amdgcn_mfma_f32_16x16x32_bf16(av0, bv1, acc[0][1], 0, 0, 0);
    acc[0][2] = __builtin_amdgcn_mfma_f32_16x16x32_bf16(av0, bv2, acc[0][2], 0, 0, 0);
    acc[0][3] = __builtin_amdgcn_mfma_f32_16x16x32_bf16(av0, bv3, acc[0][3], 0, 0, 0);
    acc[1][0] = __builtin_amdgcn_mfma_f32_16x16x32_bf16(av1, bv0, acc[1][0], 0, 0, 0);
    acc[1][1] = __builtin_amdgcn_mfma_f32_16x16x32_bf16(av1, bv1, acc[1][1], 0, 0, 0);
    acc[1][2] = __builtin_amdgcn_mfma_f32_16x16x32_bf16(av1, bv2, acc[1][2], 0, 0, 0);
    acc[1][3] = __builtin_amdgcn_mfma_f32_16x16x32_bf16(av1, bv3, acc[1][3], 0, 0, 0);
    acc[2][0] = __builtin_amdgcn_mfma_f32_16x16x32_bf16(av2, bv0, acc[2][0], 0, 0, 0);
    acc[2][1] = __builtin_amdgcn_mfma_f32_16x16x32_bf16(av2, bv1, acc[2][1], 0, 0, 0);
    acc[2][2] = __builtin_amdgcn_mfma_f32_16x16x32_bf16(av2, bv2, acc[2][2], 0, 0, 0);
    acc[2][3] = __builtin_amdgcn_mfma_f32_16x16x32_bf16(av2, bv3, acc[2][3], 0, 0, 0);
    acc[3][0] = __builtin_amdgcn_mfma_f32_16x16x32_bf16(av3, bv0, acc[3][0], 0, 0, 0);
    acc[3][1] = __builtin_amdgcn_mfma_f32_16x16x32_bf16(av3, bv1, acc[3][1], 0, 0, 0);
    acc[3][2] = __builtin_amdgcn_mfma_f32_16x16x32_bf16(av3, bv2, acc[3][2], 0, 0, 0);
    acc[3][3] = __builtin_amdgcn_mfma_f32_16x16x32_bf16(av3, bv3, acc[3][3], 0, 0, 0);
  }

  // ---- row epilogue: exact (m, l) for this wave's 64 rows over its 64 cols
  #pragma unroll
  for (int mf = 0; mf < 4; ++mf) {
    #pragma unroll
    for (int reg = 0; reg < 4; ++reg) {
      float v0 = acc[mf][0][reg];
      float v1 = acc[mf][1][reg];
      float v2 = acc[mf][2][reg];
      float v3 = acc[mf][3][reg];
      if (diag64) {
        const int rloc = mf * 16 + g * 4 + reg;   // row within 64-chunk
        v0 = (rloc == l15)      ? -1e30f : v0;
        v1 = (rloc == 16 + l15) ? -1e30f : v1;
        v2 = (rloc == 32 + l15) ? -1e30f : v2;
        v3 = (rloc == 48 + l15) ? -1e30f : v3;
      }
      float m = fmaxf(fmaxf(v0, v1), fmaxf(v2, v3)) * C2;
      #pragma unroll
      for (int s = 1; s < 16; s <<= 1) m = fmaxf(m, __shfl_xor(m, s));  // across l15
      float p = exp2f(__builtin_fmaf(v0, C2, -m)) + exp2f(__builtin_fmaf(v1, C2, -m))
              + exp2f(__builtin_fmaf(v2, C2, -m)) + exp2f(__builtin_fmaf(v3, C2, -m));
      #pragma unroll
      for (int s = 1; s < 16; s <<= 1) p += __shfl_xor(p, s);
      if (l15 == 0) {
        const int row = a * 64 + mf * 16 + g * 4 + reg;
        partM[row * NPART + b] = m;
        partL[row * NPART + b] = p;
      }
    }
  }

  // ---- col epilogue (off-diagonal blocks only; diag blocks cover the
  //      transpose chunk via waves (0,1)/(1,0) doing direct row-epi)
  if (!diagblk) {
    #pragma unroll
    for (int nf = 0; nf < 4; ++nf) {
      float m = -1e30f;
      #pragma unroll
      for (int mf = 0; mf < 4; ++mf)
        #pragma unroll
        for (int reg = 0; reg < 4; ++reg) m = fmaxf(m, acc[mf][nf][reg]);
      m *= C2;
      m = fmaxf(m, __shfl_xor(m, 16));   // across g
      m = fmaxf(m, __shfl_xor(m, 32));
      float p = 0.f;
      #pragma unroll
      for (int mf = 0; mf < 4; ++mf)
        #pragma unroll
        for (int reg = 0; reg < 4; ++reg)
          p += exp2f(__builtin_fmaf(acc[mf][nf][reg], C2, -m));
      p += __shfl_xor(p, 16);
      p += __shfl_xor(p, 32);
      if (g == 0) {
        const int row = b * 64 + nf * 16 + l15;   // column index = LSE row
        partM[row * NPART + a] = m;
        partL[row * NPART + a] = p;
      }
    }
  }
}

// ---------- kernel 4: merge 128 partials/row + nrm-part of positive term ----------
__global__ __launch_bounds__(256) void k_merge(const int* __restrict__ lab,
                                               const float* __restrict__ nrm,
                                               const float* __restrict__ partM,
                                               const float* __restrict__ partL,
                                               const int* __restrict__ cnt,
                                               float* __restrict__ blkout) {
  __shared__ float red[4];
  const int tid = threadIdx.x;
  const int lane = tid & 63;
  const int wid = tid >> 6;
  const int row = blockIdx.x * 4 + wid;

  float m1 = partM[row * NPART + lane];
  float l1 = partL[row * NPART + lane];
  const float m2 = partM[row * NPART + 64 + lane];
  const float l2 = partL[row * NPART + 64 + lane];
  float m = fmaxf(m1, m2);
  float l = l1 * exp2f(m1 - m) + l2 * exp2f(m2 - m);
  #pragma unroll
  for (int s = 1; s < 64; s <<= 1) {
    const float mo = __shfl_xor(m, s);
    const float lo = __shfl_xor(l, s);
    const float mn = fmaxf(m, mo);
    l = l * exp2f(m - mn) + lo * exp2f(mo - mn);
    m = mn;
  }
  if (lane == 0) {
    const float lse = 0.6931471805599453f * (m + log2f(l));  // natural-log LSE
    const int lbl = lab[row];
    const float pc = (float)(cnt[lbl] - 1);
    red[wid] = -nrm[row] * 10.0f / pc - lse;   // pos dot-part handled in k_final
  }
  __syncthreads();
  if (tid == 0) blkout[blockIdx.x] = red[0] + red[1] + red[2] + red[3];
}

// ---------- kernel 5: final reduce + class-norm positive part ----------
__global__ __launch_bounds__(256) void k_final(const float* __restrict__ blkout,
                                               const float* __restrict__ Cls,
                                               const int* __restrict__ cnt,
                                               float* __restrict__ out) {
  __shared__ float w[4];
  const int t = threadIdx.x;
  float s = 0.f;
  #pragma unroll
  for (int k = 0; k < 8; ++k) s += blkout[t + 256 * k];
  #pragma unroll
  for (int c = 0; c < 16; ++c) {
    const float2 v = *(const float2*)(Cls + c * DIM + t * 2);
    const float wc = 10.0f / (float)(cnt[c] - 1);
    s += wc * (v.x * v.x + v.y * v.y);
  }
  #pragma unroll
  for (int sh = 1; sh < 64; sh <<= 1) s += __shfl_xor(s, sh);
  if ((t & 63) == 0) w[t >> 6] = s;
  __syncthreads();
  if (t == 0) out[0] = (w[0] + w[1] + w[2] + w[3]) * (-0.1f / 8192.0f);
}

extern "C" void kernel_launch(void* const* d_in, const int* in_sizes, int n_in,
                              void* d_out, int out_size, void* d_ws, size_t ws_size,
                              hipStream_t stream) {
  (void)in_sizes; (void)n_in; (void)out_size; (void)ws_size;
  const float* E  = (const float*)d_in[0];
  const int* lab  = (const int*)d_in[1];
  char* ws = (char*)d_ws;
  unsigned short* Ebf = (unsigned short*)(ws + OFF_EBF);
  float* Cprt = (float*)(ws + OFF_X);
  float* pM   = (float*)(ws + OFF_PM);
  float* pL   = (float*)(ws + OFF_PL);
  float* Cls  = (float*)(ws + OFF_CLS);
  int*   cnt  = (int*)  (ws + OFF_CNT);
  float* nrm  = (float*)(ws + OFF_NRM);
  float* blk  = (float*)(ws + OFF_BLK);

  hipMemsetAsync(ws + OFF_CNT, 0, 64, stream);   // cnt only

  k_prep  <<<NROWS / 4, 256, 0, stream>>>(E, Ebf, nrm);
  k_cls   <<<128, 256, 0, stream>>>(E, lab, Cprt, cnt);
  k_clsred<<<32, 256, 0, stream>>>(Cprt, Cls);
  dim3 grid(65, 32);
  k_main  <<<grid, 256, 0, stream>>>(Ebf, pM, pL);
  k_merge <<<NROWS / 4, 256, 0, stream>>>(lab, nrm, pM, pL, cnt, blk);
  k_final <<<1, 256, 0, stream>>>(blk, Cls, cnt, (float*)d_out);
}

// Round 9
// 202.435 us; speedup vs baseline: 1.4316x; 1.4316x over previous
//
#include <hip/hip_runtime.h>
#include <stdint.h>

#define NROWS 8192
#define DIM   512
#define NPART 128          // one slot per 64-column chunk

typedef __attribute__((ext_vector_type(8))) short short8;
typedef __attribute__((ext_vector_type(4))) float f32x4;
typedef unsigned int u32;

// ws layout (bytes). CPART shares space with PM/PL (disjoint lifetimes).
#define OFF_EBF   0u           // 8192*512*2 = 8388608
#define OFF_X     8388608u     // CPART 8 MB (dead after k_clsred)
#define OFF_PM    8388608u     // 8192*128*4 = 4 MB
#define OFF_PL    12582912u    // 4 MB
#define OFF_CLS   16777216u    // 16*512*4 = 32768
#define OFF_CNT   16809984u    // 64
#define OFF_NRM   16810048u    // 8192*4 = 32768
#define OFF_BLK   16842816u    // 2048*4 = 8192

__device__ __forceinline__ void gload16(const void* g, void* l) {
  __builtin_amdgcn_global_load_lds((const __attribute__((address_space(1))) u32*)g,
                                   (__attribute__((address_space(3))) u32*)l, 16, 0, 0);
}

__device__ __forceinline__ unsigned short f2bf(float f) {
  u32 u = __float_as_uint(f);
  u32 r = (u + 0x7fffu + ((u >> 16) & 1u)) >> 16;
  return (unsigned short)r;
}

// ---------- kernel 1: fp32 -> bf16 + row norms^2 ----------
__global__ __launch_bounds__(256) void k_prep(const float* __restrict__ E,
                                              unsigned short* __restrict__ Ebf,
                                              float* __restrict__ nrm) {
  const int tid = threadIdx.x;
  const int lane = tid & 63;
  const int wid = tid >> 6;
  const int row = blockIdx.x * 4 + wid;
  const float4* src = (const float4*)(E + row * DIM + lane * 8);
  float4 v0 = src[0], v1 = src[1];
  float ns = v0.x*v0.x + v0.y*v0.y + v0.z*v0.z + v0.w*v0.w
           + v1.x*v1.x + v1.y*v1.y + v1.z*v1.z + v1.w*v1.w;
  u32 p0 = (u32)f2bf(v0.x) | ((u32)f2bf(v0.y) << 16);
  u32 p1 = (u32)f2bf(v0.z) | ((u32)f2bf(v0.w) << 16);
  u32 p2 = (u32)f2bf(v1.x) | ((u32)f2bf(v1.y) << 16);
  u32 p3 = (u32)f2bf(v1.z) | ((u32)f2bf(v1.w) << 16);
  *(uint4*)(Ebf + row * DIM + lane * 8) = make_uint4(p0, p1, p2, p3);
  #pragma unroll
  for (int s = 1; s < 64; s <<= 1) ns += __shfl_xor(ns, s);
  if (lane == 0) nrm[row] = ns;
}

// ---------- kernel 2: class partial sums from Ebf via LDS float atomics ----------
__global__ __launch_bounds__(256) void k_cls(const unsigned short* __restrict__ Ebf,
                                             const int* __restrict__ lab,
                                             float* __restrict__ Cpart,
                                             int* __restrict__ cnt) {
  __shared__ float lcls[16 * DIM];
  __shared__ int lcnt[16];
  const int t = threadIdx.x;          // owns dims {2t, 2t+1}
  const int b = blockIdx.x;           // 256 blocks x 32 rows
  const int i0 = b * 32;
  for (int k = t; k < 16 * DIM; k += 256) lcls[k] = 0.f;
  if (t < 16) lcnt[t] = 0;
  __syncthreads();
  if (t < 32) atomicAdd(&lcnt[lab[i0 + t]], 1);
  for (int r = 0; r < 32; ++r) {
    const int lbl = lab[i0 + r];
    const ushort2 v = *(const ushort2*)(Ebf + (i0 + r) * DIM + t * 2);
    atomicAdd(&lcls[lbl * DIM + t * 2],     __uint_as_float((u32)v.x << 16));
    atomicAdd(&lcls[lbl * DIM + t * 2 + 1], __uint_as_float((u32)v.y << 16));
  }
  __syncthreads();
  for (int k = t; k < 16 * DIM; k += 256) Cpart[b * 8192 + k] = lcls[k];
  if (t < 16) atomicAdd(&cnt[t], lcnt[t]);
}

// ---------- kernel 2b: reduce class partials ----------
__global__ __launch_bounds__(256) void k_clsred(const float* __restrict__ Cpart,
                                                float* __restrict__ Cls) {
  const int idx = blockIdx.x * 256 + threadIdx.x;   // 32 blocks -> 8192 = 16*512
  float s = 0.f;
  #pragma unroll 8
  for (int b = 0; b < 256; ++b) s += Cpart[b * 8192 + idx];
  Cls[idx] = s;
}

// ---------- kernel 3: triangle via uniform strip-pairs, r3 inner structure ----------
// Strip-pair p: row-tile p (j = p..63) + row-tile 63-p (j = 63-p..63), 65 tiles.
// 32 chunks/strip -> 1024 blocks x 2-3 tiles, 4 blocks/CU resident.
__global__ __launch_bounds__(256) void k_main(const unsigned short* __restrict__ Ebf,
                                              float* __restrict__ partM,
                                              float* __restrict__ partL) {
  __shared__ __align__(16) unsigned short As[128 * 64];
  __shared__ __align__(16) unsigned short Bs[128 * 64];

  const int bid = blockIdx.x;
  const int p = bid & 31;          // strip-pair
  const int c = bid >> 5;          // chunk 0..31
  const int nq  = (c == 0) ? 3 : 2;
  const int off = (c == 0) ? 0 : (2 * c + 1);

  const int tid  = threadIdx.x;
  const int lane = tid & 63;
  const int wid  = tid >> 6;
  const int wm   = wid >> 1;   // wave row 0..1
  const int wn   = wid & 1;    // wave col 0..1
  const int g    = lane >> 4;  // 0..3
  const int l15  = lane & 15;

  const float C2 = 14.4269504088896f;  // (1/T) * log2(e)

  // staging geometry: round r, thread tid covers LDS bytes D = r*4096 + tid*16
  int srow[4], selem[4];
  #pragma unroll
  for (int r = 0; r < 4; ++r) {
    const int D   = r * 4096 + tid * 16;
    const int row = D >> 7;             // 0..127 (row stride 128B = 64 bf16)
    const int cb  = (D >> 4) & 7;       // 16B chunk within row
    const int cs  = cb ^ (row & 7);     // pre-swizzled source chunk
    srow[r]  = row;
    selem[r] = cs * 8;                  // bf16 elements
  }

  for (int qq = 0; qq < nq; ++qq) {
    const int q = off + qq;            // concat position 0..64
    const int len1 = 64 - p;           // strip 1 length
    const int it = (q < len1) ? p : 63 - p;
    const int jt = (q < len1) ? p + q : (63 - p) + (q - len1);
    const int i0 = it * 128;
    const int j0 = jt * 128;
    const bool diagt = (it == jt);

    f32x4 acc[4][4];
    #pragma unroll
    for (int a = 0; a < 4; ++a)
      #pragma unroll
      for (int b = 0; b < 4; ++b) {
        f32x4 z = {0.f, 0.f, 0.f, 0.f};
        acc[a][b] = z;
      }

    for (int kc = 0; kc < 8; ++kc) {
      #pragma unroll
      for (int r = 0; r < 4; ++r) {
        gload16(Ebf + (i0 + srow[r]) * DIM + kc * 64 + selem[r], &As[r * 2048 + tid * 8]);
        gload16(Ebf + (j0 + srow[r]) * DIM + kc * 64 + selem[r], &Bs[r * 2048 + tid * 8]);
      }
      __syncthreads();   // drains vmcnt: LDS tiles ready

      #pragma unroll
      for (int ks = 0; ks < 2; ++ks) {
        const int x = ((ks << 2) | g) ^ (l15 & 7);
        short8 av[4], bv[4];
        #pragma unroll
        for (int mf = 0; mf < 4; ++mf)
          av[mf] = *(const short8*)&As[(wm * 64 + mf * 16 + l15) * 64 + x * 8];
        #pragma unroll
        for (int nf = 0; nf < 4; ++nf)
          bv[nf] = *(const short8*)&Bs[(wn * 64 + nf * 16 + l15) * 64 + x * 8];
        #pragma unroll
        for (int mf = 0; mf < 4; ++mf)
          #pragma unroll
          for (int nf = 0; nf < 4; ++nf)
            acc[mf][nf] = __builtin_amdgcn_mfma_f32_16x16x32_bf16(av[mf], bv[nf], acc[mf][nf], 0, 0, 0);
      }
      __syncthreads();   // safe to overwrite LDS next round
    }

    // ---- row epilogue: exact (m, l) for this wave's 64 rows over its 64 cols
    #pragma unroll
    for (int mf = 0; mf < 4; ++mf) {
      #pragma unroll
      for (int reg = 0; reg < 4; ++reg) {
        float v0 = acc[mf][0][reg];
        float v1 = acc[mf][1][reg];
        float v2 = acc[mf][2][reg];
        float v3 = acc[mf][3][reg];
        if (diagt) {
          const int rloc  = wm * 64 + mf * 16 + g * 4 + reg;  // row within 128-tile
          const int cbase = wn * 64 + l15;                    // col base within 128-tile
          v0 = (rloc == cbase)      ? -1e30f : v0;
          v1 = (rloc == cbase + 16) ? -1e30f : v1;
          v2 = (rloc == cbase + 32) ? -1e30f : v2;
          v3 = (rloc == cbase + 48) ? -1e30f : v3;
        }
        float m = fmaxf(fmaxf(v0, v1), fmaxf(v2, v3)) * C2;
        #pragma unroll
        for (int s = 1; s < 16; s <<= 1) m = fmaxf(m, __shfl_xor(m, s));  // across l15
        float pp = exp2f(__builtin_fmaf(v0, C2, -m)) + exp2f(__builtin_fmaf(v1, C2, -m))
                 + exp2f(__builtin_fmaf(v2, C2, -m)) + exp2f(__builtin_fmaf(v3, C2, -m));
        #pragma unroll
        for (int s = 1; s < 16; s <<= 1) pp += __shfl_xor(pp, s);
        if (l15 == 0) {
          const int row = i0 + wm * 64 + mf * 16 + g * 4 + reg;
          partM[row * NPART + jt * 2 + wn] = m;
          partL[row * NPART + jt * 2 + wn] = pp;
        }
      }
    }

    // ---- col epilogue (off-diagonal tiles only)
    if (!diagt) {
      #pragma unroll
      for (int nf = 0; nf < 4; ++nf) {
        float m = -1e30f;
        #pragma unroll
        for (int mf = 0; mf < 4; ++mf)
          #pragma unroll
          for (int reg = 0; reg < 4; ++reg) m = fmaxf(m, acc[mf][nf][reg]);
        m *= C2;
        m = fmaxf(m, __shfl_xor(m, 16));   // across g
        m = fmaxf(m, __shfl_xor(m, 32));
        float pp = 0.f;
        #pragma unroll
        for (int mf = 0; mf < 4; ++mf)
          #pragma unroll
          for (int reg = 0; reg < 4; ++reg)
            pp += exp2f(__builtin_fmaf(acc[mf][nf][reg], C2, -m));
        pp += __shfl_xor(pp, 16);
        pp += __shfl_xor(pp, 32);
        if (g == 0) {
          const int row = j0 + wn * 64 + nf * 16 + l15;   // column index = LSE row
          partM[row * NPART + it * 2 + wm] = m;
          partL[row * NPART + it * 2 + wm] = pp;
        }
      }
    }
  }
}

// ---------- kernel 4: merge 128 partials/row + nrm-part of positive term ----------
__global__ __launch_bounds__(256) void k_merge(const int* __restrict__ lab,
                                               const float* __restrict__ nrm,
                                               const float* __restrict__ partM,
                                               const float* __restrict__ partL,
                                               const int* __restrict__ cnt,
                                               float* __restrict__ blkout) {
  __shared__ float red[4];
  const int tid = threadIdx.x;
  const int lane = tid & 63;
  const int wid = tid >> 6;
  const int row = blockIdx.x * 4 + wid;

  float m1 = partM[row * NPART + lane];
  float l1 = partL[row * NPART + lane];
  const float m2 = partM[row * NPART + 64 + lane];
  const float l2 = partL[row * NPART + 64 + lane];
  float m = fmaxf(m1, m2);
  float l = l1 * exp2f(m1 - m) + l2 * exp2f(m2 - m);
  #pragma unroll
  for (int s = 1; s < 64; s <<= 1) {
    const float mo = __shfl_xor(m, s);
    const float lo = __shfl_xor(l, s);
    const float mn = fmaxf(m, mo);
    l = l * exp2f(m - mn) + lo * exp2f(mo - mn);
    m = mn;
  }
  if (lane == 0) {
    const float lse = 0.6931471805599453f * (m + log2f(l));  // natural-log LSE
    const int lbl = lab[row];
    const float pc = (float)(cnt[lbl] - 1);
    red[wid] = -nrm[row] * 10.0f / pc - lse;   // pos dot-part handled in k_final
  }
  __syncthreads();
  if (tid == 0) blkout[blockIdx.x] = red[0] + red[1] + red[2] + red[3];
}

// ---------- kernel 5: final reduce + class-norm positive part ----------
__global__ __launch_bounds__(256) void k_final(const float* __restrict__ blkout,
                                               const float* __restrict__ Cls,
                                               const int* __restrict__ cnt,
                                               float* __restrict__ out) {
  __shared__ float w[4];
  const int t = threadIdx.x;
  float s = 0.f;
  #pragma unroll
  for (int k = 0; k < 8; ++k) s += blkout[t + 256 * k];
  #pragma unroll
  for (int c = 0; c < 16; ++c) {
    const float2 v = *(const float2*)(Cls + c * DIM + t * 2);
    const float wc = 10.0f / (float)(cnt[c] - 1);
    s += wc * (v.x * v.x + v.y * v.y);
  }
  #pragma unroll
  for (int sh = 1; sh < 64; sh <<= 1) s += __shfl_xor(s, sh);
  if ((t & 63) == 0) w[t >> 6] = s;
  __syncthreads();
  if (t == 0) out[0] = (w[0] + w[1] + w[2] + w[3]) * (-0.1f / 8192.0f);
}

extern "C" void kernel_launch(void* const* d_in, const int* in_sizes, int n_in,
                              void* d_out, int out_size, void* d_ws, size_t ws_size,
                              hipStream_t stream) {
  (void)in_sizes; (void)n_in; (void)out_size; (void)ws_size;
  const float* E  = (const float*)d_in[0];
  const int* lab  = (const int*)d_in[1];
  char* ws = (char*)d_ws;
  unsigned short* Ebf = (unsigned short*)(ws + OFF_EBF);
  float* Cprt = (float*)(ws + OFF_X);
  float* pM   = (float*)(ws + OFF_PM);
  float* pL   = (float*)(ws + OFF_PL);
  float* Cls  = (float*)(ws + OFF_CLS);
  int*   cnt  = (int*)  (ws + OFF_CNT);
  float* nrm  = (float*)(ws + OFF_NRM);
  float* blk  = (float*)(ws + OFF_BLK);

  hipMemsetAsync(ws + OFF_CNT, 0, 64, stream);   // cnt only

  k_prep  <<<NROWS / 4, 256, 0, stream>>>(E, Ebf, nrm);
  k_cls   <<<256, 256, 0, stream>>>(Ebf, lab, Cprt, cnt);
  k_clsred<<<32, 256, 0, stream>>>(Cprt, Cls);
  k_main  <<<1024, 256, 0, stream>>>(Ebf, pM, pL);
  k_merge <<<NROWS / 4, 256, 0, stream>>>(lab, nrm, pM, pL, cnt, blk);
  k_final <<<1, 256, 0, stream>>>(blk, Cls, cnt, (float*)d_out);
}